// Round 5
// baseline (226.535 us; speedup 1.0000x reference)
//
#include <hip/hip_runtime.h>
#include <hip/hip_bf16.h>
#include <math.h>

typedef unsigned short u16;
typedef unsigned int u32;
typedef __bf16 bf16x8 __attribute__((ext_vector_type(8)));
typedef float f32x4 __attribute__((ext_vector_type(4)));

// B=8, T=128, S=512, E=D=512, fp32 in/out. d_out: h_tilde | wc | attn (fp32).
#define OUT_WC   524288LL
#define OUT_ATTN 1048576LL
#define C2 2.8853900817779268f   // 2*log2(e)
#define LOG2E 1.4426950408889634f
#define LAS 40                   // LDS row stride (u16): 32 + 8 pad

__device__ inline u16 f2b(float f) {
    return (u16)((__float_as_uint(f) + 0x8000u) >> 16);
}
__device__ inline float b2f(u16 v) { return __uint_as_float(((u32)v) << 16); }
__device__ inline u32 pkcvt(float x, float y) {
    __hip_bfloat162 h = __float22bfloat162_rn(make_float2(x, y));
    return *(u32*)&h;
}
__device__ inline float tanh_fast(float x) {
    return 1.f - 2.f * __builtin_amdgcn_rcpf(__builtin_amdgcn_exp2f(C2 * x) + 1.f);
}

// =============== proj: ept + hp + hh fused, 768 blocks, 64x64 tiles ==========
// fp32 inputs, inline bf16 convert during LDS staging (tobf kernel deleted).
// mode 0 by==0 blocks side-write their converted enc B-tile to enc_bf
// (each enc row converted exactly once) for the energies wc phase.
__global__ __launch_bounds__(256) void proj(
    const float* __restrict__ hidden, const float* __restrict__ enc,
    const float* __restrict__ Wattn, const float* __restrict__ battn,
    const float* __restrict__ Wout,
    float* __restrict__ hp, u16* __restrict__ ept, float* __restrict__ hh,
    u16* __restrict__ enc_bf)
{
    __shared__ u16 lA[64 * LAS];
    __shared__ u16 lB[64 * LAS];
    const int tid = threadIdx.x;
    const int wvi = tid >> 6, ln = tid & 63;
    const int wm = wvi >> 1, wn = wvi & 1;
    const int l16 = ln & 15, quad = ln >> 4;
    const int blk = blockIdx.x;
    int bx, by, zz = 0, lda, ldb, mode;
    const float *A, *B;
    if (blk < 512) {
        mode = 0;
        zz = blk >> 6; by = (blk >> 3) & 7; bx = blk & 7;
        A = Wattn + 512; lda = 1024;
        B = enc + (long long)zz * 262144; ldb = 512;
    } else if (blk < 640) {
        mode = 1;
        int i = blk - 512; by = i >> 3; bx = i & 7;
        A = hidden; lda = 512;
        B = Wattn; ldb = 1024;
    } else {
        mode = 2;
        int i = blk - 640; by = i >> 3; bx = i & 7;
        A = hidden; lda = 512;
        B = Wout + 512; ldb = 1024;
    }
    const int m0 = by * 64, n0 = bx * 64;
    const int srow = tid >> 2, skof = (tid & 3) * 8;
    const float* Ap = A + (long long)(m0 + srow) * lda + skof;
    const float* Bp = B + (long long)(n0 + srow) * ldb + skof;
    const bool wr_enc = (mode == 0) && (by == 0);

    f32x4 acc00 = {0,0,0,0}, acc01 = {0,0,0,0}, acc10 = {0,0,0,0}, acc11 = {0,0,0,0};

    for (int k0 = 0; k0 < 512; k0 += 32) {
        float4 af0 = *(const float4*)(Ap + k0);
        float4 af1 = *(const float4*)(Ap + k0 + 4);
        float4 bf0 = *(const float4*)(Bp + k0);
        float4 bf1 = *(const float4*)(Bp + k0 + 4);
        uint4 av = make_uint4(pkcvt(af0.x, af0.y), pkcvt(af0.z, af0.w),
                              pkcvt(af1.x, af1.y), pkcvt(af1.z, af1.w));
        uint4 bv = make_uint4(pkcvt(bf0.x, bf0.y), pkcvt(bf0.z, bf0.w),
                              pkcvt(bf1.x, bf1.y), pkcvt(bf1.z, bf1.w));
        if (wr_enc)
            *(uint4*)(enc_bf + (long long)zz * 262144 +
                      (long long)(n0 + srow) * 512 + k0 + skof) = bv;
        __syncthreads();
        *(uint4*)&lA[srow * LAS + skof] = av;
        *(uint4*)&lB[srow * LAS + skof] = bv;
        __syncthreads();
        bf16x8 a0 = *(const bf16x8*)&lA[(wm * 32      + l16) * LAS + quad * 8];
        bf16x8 a1 = *(const bf16x8*)&lA[(wm * 32 + 16 + l16) * LAS + quad * 8];
        bf16x8 b0 = *(const bf16x8*)&lB[(wn * 32      + l16) * LAS + quad * 8];
        bf16x8 b1 = *(const bf16x8*)&lB[(wn * 32 + 16 + l16) * LAS + quad * 8];
        acc00 = __builtin_amdgcn_mfma_f32_16x16x32_bf16(a0, b0, acc00, 0, 0, 0);
        acc01 = __builtin_amdgcn_mfma_f32_16x16x32_bf16(a0, b1, acc01, 0, 0, 0);
        acc10 = __builtin_amdgcn_mfma_f32_16x16x32_bf16(a1, b0, acc10, 0, 0, 0);
        acc11 = __builtin_amdgcn_mfma_f32_16x16x32_bf16(a1, b1, acc11, 0, 0, 0);
    }

    const f32x4* accs[4] = { &acc00, &acc01, &acc10, &acc11 };
    #pragma unroll
    for (int i = 0; i < 2; ++i) {
        #pragma unroll
        for (int j = 0; j < 2; ++j) {
            const f32x4& a = *accs[i * 2 + j];
            #pragma unroll
            for (int r = 0; r < 4; ++r) {
                int m = m0 + wm * 32 + i * 16 + quad * 4 + r;
                int n = n0 + wn * 32 + j * 16 + l16;
                float v = a[r];
                if (mode == 0)
                    ept[(long long)zz * 262144 + (long long)m * 512 + n] =
                        f2b(__builtin_amdgcn_exp2f(C2 * v));
                else if (mode == 1)
                    hp[(long long)m * 512 + n] = C2 * (v + battn[n]);
                else
                    hh[(long long)m * 512 + n] = v;
            }
        }
    }
}

// =============== wave reductions ============================================
__device__ inline float wred_sum(float v) {
    #pragma unroll
    for (int i = 32; i > 0; i >>= 1) v += __shfl_xor(v, i);
    return v;
}
__device__ inline float wred_max(float v) {
    #pragma unroll
    for (int i = 32; i > 0; i >>= 1) v = fmaxf(v, __shfl_xor(v, i));
    return v;
}

// =============== energies + masked softmax + wc (fused, dual-t) ==============
// 512 blocks (b x t-pair) x 1024 threads (16 waves). LDS cut to ~16.3KB
// (r4's 64KB pa buffer replaced by ds_add_f32 into accE[2][512]) so
// 2 blocks/CU co-reside -> 32 waves/CU. Atomic index rotated by lane so
// each ds_add instruction spans all 32 banks (2-way aliasing = free).
// b = bid & 7: XCD-grouped (ept[b]+enc_bf[b] ~1MB fits the 4MB XCD L2).
__device__ inline void proc8(uint4 c, float4 hw, float* a0, float* a1) {
    u32 cc[4] = {c.x, c.y, c.z, c.w};
    #pragma unroll
    for (int i = 0; i < 4; ++i) {
        float xl = __uint_as_float(cc[i] << 16);
        float xh = __uint_as_float(cc[i] & 0xFFFF0000u);
        float rl0 = __builtin_amdgcn_rcpf(fmaf(hw.x, xl, 1.f));
        float rh0 = __builtin_amdgcn_rcpf(fmaf(hw.x, xh, 1.f));
        float rl1 = __builtin_amdgcn_rcpf(fmaf(hw.y, xl, 1.f));
        float rh1 = __builtin_amdgcn_rcpf(fmaf(hw.y, xh, 1.f));
        a0[2*i]   = fmaf(hw.z, rl0, a0[2*i]);
        a0[2*i+1] = fmaf(hw.z, rh0, a0[2*i+1]);
        a1[2*i]   = fmaf(hw.z, rl1, a1[2*i]);
        a1[2*i+1] = fmaf(hw.z, rh1, a1[2*i+1]);
    }
}
__device__ inline void wcproc2(uint4 c, float2 ap, float* acc0, float* acc1) {
    u32 cc[4] = {c.x, c.y, c.z, c.w};
    #pragma unroll
    for (int i = 0; i < 4; ++i) {
        float el = __uint_as_float(cc[i] << 16);
        float eh = __uint_as_float(cc[i] & 0xFFFF0000u);
        acc0[2*i]   = fmaf(ap.x, el, acc0[2*i]);
        acc0[2*i+1] = fmaf(ap.x, eh, acc0[2*i+1]);
        acc1[2*i]   = fmaf(ap.y, el, acc1[2*i]);
        acc1[2*i+1] = fmaf(ap.y, eh, acc1[2*i+1]);
    }
}

__global__ __launch_bounds__(1024) void energies(
    const float* __restrict__ maskp, const float* __restrict__ hp,
    const u16* __restrict__ ept, const float* __restrict__ Wv,
    const float* __restrict__ bvp, const u16* __restrict__ enc_bf,
    float* __restrict__ attn, float* __restrict__ wc)
{
    __shared__ __align__(16) float4 hpw[512];   // (e^{2hp_t0}, e^{2hp_t1}, Wv, -) 8KB
    __shared__ float accE[2][512];              // 4KB atomic accumulators (E, then wc)
    __shared__ float aL[512][2];                // 4KB attn weights for wc
    __shared__ float red[16];
    const int tid = threadIdx.x;
    const int b  = blockIdx.x & 7;              // XCD-grouped
    const int t0 = (blockIdx.x >> 3) * 2;
    const int th = tid >> 9;                    // 0: waves 0-7 (t0), 1: waves 8-15 (t0+1)
    const int k5 = tid & 511;
    const long long row0 = (long long)(b * 128 + t0) * 512;

    // ---- setup: zero accE, hpw + sumWv ----
    ((float*)accE)[tid] = 0.f;
    float hv = hp[row0 + (long long)th * 512 + k5];
    float ehv = __builtin_amdgcn_exp2f(hv);
    float* hpwf = (float*)hpw;
    hpwf[k5 * 4 + th] = ehv;
    float w = 0.f;
    if (th == 0) { w = Wv[k5]; hpwf[k5 * 4 + 2] = w; }
    float wsum = wred_sum(w);
    if ((tid & 63) == 0) red[tid >> 6] = wsum;  // th==1 waves write 0: harmless
    __syncthreads();                            // hpw + red + zeroed accE visible
    float sumWv = 0.f;
    #pragma unroll
    for (int i = 0; i < 16; ++i) sumWv += red[i];

    // ---- main loop: A[s] = sum_k Wv_k / (e^{2hp}*e^{2ep} + 1), both t ----
    const int kg = tid >> 6, sl = tid & 63;     // kg = wave: 32 k-rows; 8 s-cols
    const int s0 = sl * 8;
    const u16* eb = ept + (long long)b * 262144 + (kg * 32) * 512 + s0;
    const float4* hq = &hpw[kg * 32];

    float a0[8] = {0,0,0,0,0,0,0,0}, a1[8] = {0,0,0,0,0,0,0,0};
    uint4 c0 = *(const uint4*)(eb);
    uint4 c1 = *(const uint4*)(eb + 512);
    for (int kk = 0; kk < 30; kk += 2) {
        const u16* nb = eb + (kk + 2) * 512;
        uint4 n0 = *(const uint4*)(nb);
        uint4 n1 = *(const uint4*)(nb + 512);
        proc8(c0, hq[kk],     a0, a1);
        proc8(c1, hq[kk + 1], a0, a1);
        c0 = n0; c1 = n1;
    }
    proc8(c0, hq[30], a0, a1);
    proc8(c1, hq[31], a0, a1);

    // rotated atomic accumulate: addr = 9*sl + i (mod 32) -> all banks hit
    #pragma unroll
    for (int i = 0; i < 8; ++i) {
        int ii = (i + sl) & 7;
        atomicAdd(&accE[0][s0 + ii], a0[ii]);
        atomicAdd(&accE[1][s0 + ii], a1[ii]);
    }
    __syncthreads();

    // ---- softmax: thread owns (t = th, s = k5); each wave is one th ----
    float A = accE[th][k5];
    float mv = maskp[(long long)b * 512 + k5];
    float bv0 = bvp[0];
    float r = (bv0 + sumWv - 2.f * A) * mv; r *= mv;

    float vmax = wred_max(r);
    if ((tid & 63) == 0) red[tid >> 6] = vmax;
    __syncthreads();
    float mx = red[th * 8];
    #pragma unroll
    for (int i = 1; i < 8; ++i) mx = fmaxf(mx, red[th * 8 + i]);

    float ex = __builtin_amdgcn_exp2f((r - mx) * LOG2E) * mv;
    float vsum = wred_sum(ex);
    __syncthreads();                            // mx reads done before red reuse
    if ((tid & 63) == 0) red[tid >> 6] = vsum;
    __syncthreads();
    float sm = 0.f;
    #pragma unroll
    for (int i = 0; i < 8; ++i) sm += red[th * 8 + i];
    float at = ex * (1.f / (sm + 1e-6f));
    attn[row0 + (long long)th * 512 + k5] = at;
    aL[k5][th] = at;
    ((float*)accE)[tid] = 0.f;                  // re-zero for wc partials
    __syncthreads();                            // aL + zeroed accE visible

    // ---- wc = attn @ enc: thread owns 8 e-cols (eg) x 32 s-rows (sg) ----
    const int eg = tid & 63, sg = tid >> 6;
    const u16* encb = enc_bf + (long long)b * 262144 + (long long)(sg * 32) * 512 + eg * 8;
    const float2* aq = (const float2*)&aL[sg * 32][0];
    float acc0[8] = {0,0,0,0,0,0,0,0}, acc1[8] = {0,0,0,0,0,0,0,0};
    uint4 e0 = *(const uint4*)(encb);
    uint4 e1 = *(const uint4*)(encb + 512);
    for (int j = 0; j < 30; j += 2) {
        uint4 f0 = *(const uint4*)(encb + (long long)(j + 2) * 512);
        uint4 f1 = *(const uint4*)(encb + (long long)(j + 3) * 512);
        wcproc2(e0, aq[j],     acc0, acc1);
        wcproc2(e1, aq[j + 1], acc0, acc1);
        e0 = f0; e1 = f1;
    }
    wcproc2(e0, aq[30], acc0, acc1);
    wcproc2(e1, aq[31], acc0, acc1);

    #pragma unroll
    for (int i = 0; i < 8; ++i) {
        int ii = (i + eg) & 7;
        atomicAdd(&accE[0][eg * 8 + ii], acc0[ii]);
        atomicAdd(&accE[1][eg * 8 + ii], acc1[ii]);
    }
    __syncthreads();

    wc[row0 + (long long)th * 512 + k5] = accE[th][k5];
}

// =============== hout: h_tilde = tanh(wc @ Wout[:,:512]^T + hh) ==============
// Wout read fp32 with inline pkcvt (Wout_bf eliminated).
__global__ __launch_bounds__(256) void hout_k(
    const float* __restrict__ wc, const float* __restrict__ Wout,
    float* __restrict__ out)
{
    __shared__ u16 lA[32 * LAS];
    __shared__ u16 lB[64 * LAS];
    const int tid = threadIdx.x;
    const int wvi = tid >> 6, ln = tid & 63;
    const int l16 = ln & 15, quad = ln >> 4;
    const int msub = wvi & 1, npair = wvi >> 1;
    const int m0 = blockIdx.y * 32, n0 = blockIdx.x * 64;
    const int rowA = tid >> 3, kofA = (tid & 7) * 4;
    const int rowB = tid >> 2, kofB = (tid & 3) * 8;
    f32x4 acc0 = {0,0,0,0}, acc1 = {0,0,0,0};

    for (int k0 = 0; k0 < 512; k0 += 32) {
        float4 av = *(const float4*)(wc + (long long)(m0 + rowA) * 512 + k0 + kofA);
        float4 bw0 = *(const float4*)(Wout + (long long)(n0 + rowB) * 1024 + k0 + kofB);
        float4 bw1 = *(const float4*)(Wout + (long long)(n0 + rowB) * 1024 + k0 + kofB + 4);
        uint4 bv = make_uint4(pkcvt(bw0.x, bw0.y), pkcvt(bw0.z, bw0.w),
                              pkcvt(bw1.x, bw1.y), pkcvt(bw1.z, bw1.w));
        __syncthreads();
        *(uint2*)&lA[rowA * LAS + kofA] = make_uint2(pkcvt(av.x, av.y), pkcvt(av.z, av.w));
        int kk = kofB ^ (((rowB >> 3) & 3) << 3);
        *(uint4*)&lB[rowB * LAS + kk] = bv;
        __syncthreads();
        bf16x8 a = *(const bf16x8*)&lA[(msub * 16 + l16) * LAS + quad * 8];
        int nr0 = npair * 32 + l16, nr1 = nr0 + 16;
        bf16x8 b0 = *(const bf16x8*)&lB[nr0 * LAS + (quad * 8 ^ (((nr0 >> 3) & 3) << 3))];
        bf16x8 b1 = *(const bf16x8*)&lB[nr1 * LAS + (quad * 8 ^ (((nr1 >> 3) & 3) << 3))];
        acc0 = __builtin_amdgcn_mfma_f32_16x16x32_bf16(a, b0, acc0, 0, 0, 0);
        acc1 = __builtin_amdgcn_mfma_f32_16x16x32_bf16(a, b1, acc1, 0, 0, 0);
    }
    #pragma unroll
    for (int j = 0; j < 2; ++j) {
        const f32x4& a = j ? acc1 : acc0;
        #pragma unroll
        for (int r = 0; r < 4; ++r) {
            int m = m0 + msub * 16 + quad * 4 + r;
            int n = n0 + npair * 32 + j * 16 + l16;
            long long idx = (long long)m * 512 + n;
            out[idx] = tanh_fast(a[r] + out[idx]);   // out[idx] holds hh
        }
    }
}

extern "C" void kernel_launch(void* const* d_in, const int* in_sizes, int n_in,
                              void* d_out, int out_size, void* d_ws, size_t ws_size,
                              hipStream_t stream)
{
    const float* hidden = (const float*)d_in[0];  // (8,128,512)
    const float* enc    = (const float*)d_in[1];  // (8,512,512)
    const float* mask   = (const float*)d_in[2];  // (8,512)
    const float* Wattn  = (const float*)d_in[3];  // (512,1024)
    const float* battn  = (const float*)d_in[4];  // (512,)
    const float* Wv     = (const float*)d_in[5];  // (512,)
    const float* bvp    = (const float*)d_in[6];  // (1,)
    const float* Wout   = (const float*)d_in[7];  // (512,1024)
    float* out = (float*)d_out;

    float* hp     = (float*)d_ws;                     // @0   2MB fp32
    u16*   ept    = (u16*)((char*)d_ws + (2 << 20));  // @2M  4MB bf16 (exp2 domain)
    u16*   enc_bf = (u16*)((char*)d_ws + (6 << 20));  // @6M  4MB bf16

    proj<<<768, 256, 0, stream>>>(hidden, enc, Wattn, battn, Wout,
                                  hp, ept, out /* hh in-place */, enc_bf);
    energies<<<512, 1024, 0, stream>>>(mask, hp, ept, Wv, bvp, enc_bf,
                                       out + OUT_ATTN, out + OUT_WC);
    hout_k<<<dim3(8, 32, 1), 256, 0, stream>>>(out + OUT_WC, Wout, out);
}

// Round 6
// 150.846 us; speedup vs baseline: 1.5018x; 1.5018x over previous
//
#include <hip/hip_runtime.h>
#include <hip/hip_bf16.h>
#include <math.h>

typedef unsigned short u16;
typedef unsigned int u32;
typedef __bf16 bf16x8 __attribute__((ext_vector_type(8)));
typedef float f32x4 __attribute__((ext_vector_type(4)));

// B=8, T=128, S=512, E=D=512, fp32 in/out. d_out: h_tilde | wc | attn (fp32).
#define OUT_WC   524288LL
#define OUT_ATTN 1048576LL
#define C2 2.8853900817779268f   // 2*log2(e)
#define LOG2E 1.4426950408889634f
#define LAS 40                   // LDS row stride (u16) for BK=32 tiles: 32 + 8
#define LAS2 72                  // LDS row stride (u16) for BK=64 tiles: 64 + 8

__device__ inline u16 f2b(float f) {
    return (u16)((__float_as_uint(f) + 0x8000u) >> 16);
}
__device__ inline float b2f(u16 v) { return __uint_as_float(((u32)v) << 16); }
__device__ inline u32 pkcvt(float x, float y) {
    __hip_bfloat162 h = __float22bfloat162_rn(make_float2(x, y));
    return *(u32*)&h;
}
__device__ inline float tanh_fast(float x) {
    return 1.f - 2.f * __builtin_amdgcn_rcpf(__builtin_amdgcn_exp2f(C2 * x) + 1.f);
}

// =============== proj: ept + hp + hh fused, 768 blocks, 64x64 tiles ==========
// Software-pipelined: register-prefetch next BK=64 k-slab while MFMAs run on
// the current one (the old load->sync->write->sync->mfma loop exposed the full
// L2 latency between barriers every k-step; small-shape GEMMs are latency-
// bound). fp32 inputs, inline bf16 convert. mode0 by==0 blocks side-write
// their converted enc B-tile to enc_bf (each enc row exactly once).
__global__ __launch_bounds__(256) void proj(
    const float* __restrict__ hidden, const float* __restrict__ enc,
    const float* __restrict__ Wattn, const float* __restrict__ battn,
    const float* __restrict__ Wout,
    float* __restrict__ hp, u16* __restrict__ ept, float* __restrict__ hh,
    u16* __restrict__ enc_bf)
{
    __shared__ u16 lA[64 * LAS2];   // 9.2KB
    __shared__ u16 lB[64 * LAS2];   // 9.2KB
    const int tid = threadIdx.x;
    const int wvi = tid >> 6, ln = tid & 63;
    const int wm = wvi >> 1, wn = wvi & 1;
    const int l16 = ln & 15, quad = ln >> 4;
    const int blk = blockIdx.x;
    int bx, by, zz = 0, lda, ldb, mode;
    const float *A, *B;
    if (blk < 512) {
        mode = 0;
        zz = blk >> 6; by = (blk >> 3) & 7; bx = blk & 7;
        A = Wattn + 512; lda = 1024;
        B = enc + (long long)zz * 262144; ldb = 512;
    } else if (blk < 640) {
        mode = 1;
        int i = blk - 512; by = i >> 3; bx = i & 7;
        A = hidden; lda = 512;
        B = Wattn; ldb = 1024;
    } else {
        mode = 2;
        int i = blk - 640; by = i >> 3; bx = i & 7;
        A = hidden; lda = 512;
        B = Wout + 512; ldb = 1024;
    }
    const int m0 = by * 64, n0 = bx * 64;
    const int srow = tid >> 2, scol = (tid & 3) * 16;   // 4 thr/row, 16 u16 each
    const float* Ap = A + (long long)(m0 + srow) * lda + scol;
    const float* Bp = B + (long long)(n0 + srow) * ldb + scol;
    const bool wr_enc = (mode == 0) && (by == 0);

    f32x4 acc00 = {0,0,0,0}, acc01 = {0,0,0,0}, acc10 = {0,0,0,0}, acc11 = {0,0,0,0};

    float4 pa0, pa1, pa2, pa3, pb0, pb1, pb2, pb3;
    #define PROJ_LOADK(k0) do { \
        pa0 = *(const float4*)(Ap + (k0));      pa1 = *(const float4*)(Ap + (k0) + 4);  \
        pa2 = *(const float4*)(Ap + (k0) + 8);  pa3 = *(const float4*)(Ap + (k0) + 12); \
        pb0 = *(const float4*)(Bp + (k0));      pb1 = *(const float4*)(Bp + (k0) + 4);  \
        pb2 = *(const float4*)(Bp + (k0) + 8);  pb3 = *(const float4*)(Bp + (k0) + 12); } while (0)

    PROJ_LOADK(0);
    for (int step = 0; step < 8; ++step) {
        uint4 av0 = make_uint4(pkcvt(pa0.x, pa0.y), pkcvt(pa0.z, pa0.w),
                               pkcvt(pa1.x, pa1.y), pkcvt(pa1.z, pa1.w));
        uint4 av1 = make_uint4(pkcvt(pa2.x, pa2.y), pkcvt(pa2.z, pa2.w),
                               pkcvt(pa3.x, pa3.y), pkcvt(pa3.z, pa3.w));
        uint4 bv0 = make_uint4(pkcvt(pb0.x, pb0.y), pkcvt(pb0.z, pb0.w),
                               pkcvt(pb1.x, pb1.y), pkcvt(pb1.z, pb1.w));
        uint4 bv1 = make_uint4(pkcvt(pb2.x, pb2.y), pkcvt(pb2.z, pb2.w),
                               pkcvt(pb3.x, pb3.y), pkcvt(pb3.z, pb3.w));
        if (wr_enc) {
            u16* ed = enc_bf + (long long)zz * 262144 +
                      (long long)(n0 + srow) * 512 + step * 64 + scol;
            *(uint4*)ed = bv0;
            *(uint4*)(ed + 8) = bv1;
        }
        __syncthreads();
        *(uint4*)&lA[srow * LAS2 + scol]     = av0;
        *(uint4*)&lA[srow * LAS2 + scol + 8] = av1;
        *(uint4*)&lB[srow * LAS2 + scol]     = bv0;
        *(uint4*)&lB[srow * LAS2 + scol + 8] = bv1;
        __syncthreads();
        if (step < 7) PROJ_LOADK((step + 1) * 64);   // overlap with MFMA section
        #pragma unroll
        for (int kh = 0; kh < 2; ++kh) {
            bf16x8 a0 = *(const bf16x8*)&lA[(wm * 32      + l16) * LAS2 + kh * 32 + quad * 8];
            bf16x8 a1 = *(const bf16x8*)&lA[(wm * 32 + 16 + l16) * LAS2 + kh * 32 + quad * 8];
            bf16x8 b0 = *(const bf16x8*)&lB[(wn * 32      + l16) * LAS2 + kh * 32 + quad * 8];
            bf16x8 b1 = *(const bf16x8*)&lB[(wn * 32 + 16 + l16) * LAS2 + kh * 32 + quad * 8];
            acc00 = __builtin_amdgcn_mfma_f32_16x16x32_bf16(a0, b0, acc00, 0, 0, 0);
            acc01 = __builtin_amdgcn_mfma_f32_16x16x32_bf16(a0, b1, acc01, 0, 0, 0);
            acc10 = __builtin_amdgcn_mfma_f32_16x16x32_bf16(a1, b0, acc10, 0, 0, 0);
            acc11 = __builtin_amdgcn_mfma_f32_16x16x32_bf16(a1, b1, acc11, 0, 0, 0);
        }
    }
    #undef PROJ_LOADK

    const f32x4* accs[4] = { &acc00, &acc01, &acc10, &acc11 };
    #pragma unroll
    for (int i = 0; i < 2; ++i) {
        #pragma unroll
        for (int j = 0; j < 2; ++j) {
            const f32x4& a = *accs[i * 2 + j];
            #pragma unroll
            for (int r = 0; r < 4; ++r) {
                int m = m0 + wm * 32 + i * 16 + quad * 4 + r;
                int n = n0 + wn * 32 + j * 16 + l16;
                float v = a[r];
                if (mode == 0)
                    ept[(long long)zz * 262144 + (long long)m * 512 + n] =
                        f2b(__builtin_amdgcn_exp2f(C2 * v));
                else if (mode == 1)
                    hp[(long long)m * 512 + n] = C2 * (v + battn[n]);
                else
                    hh[(long long)m * 512 + n] = v;
            }
        }
    }
}

// =============== wave reductions ============================================
__device__ inline float wred_sum(float v) {
    #pragma unroll
    for (int i = 32; i > 0; i >>= 1) v += __shfl_xor(v, i);
    return v;
}
__device__ inline float wred_max(float v) {
    #pragma unroll
    for (int i = 32; i > 0; i >>= 1) v = fmaxf(v, __shfl_xor(v, i));
    return v;
}

// =============== energies + masked softmax + wc (fused, dual-t) ==============
// r4 version verbatim (best measured: 54us). 512 blocks x 1024 threads,
// staged pa[2][16][512] partials (LDS atomics regressed 2.4x in r5; 1024-thr
// blocks cap at ~1 resident regardless of LDS, so big LDS is free here).
// b = bid & 7: XCD-grouped (ept[b]+enc_bf[b] ~1MB fits the 4MB XCD L2).
__device__ inline void proc8(uint4 c, float4 hw, float* a0, float* a1) {
    u32 cc[4] = {c.x, c.y, c.z, c.w};
    #pragma unroll
    for (int i = 0; i < 4; ++i) {
        float xl = __uint_as_float(cc[i] << 16);
        float xh = __uint_as_float(cc[i] & 0xFFFF0000u);
        float rl0 = __builtin_amdgcn_rcpf(fmaf(hw.x, xl, 1.f));
        float rh0 = __builtin_amdgcn_rcpf(fmaf(hw.x, xh, 1.f));
        float rl1 = __builtin_amdgcn_rcpf(fmaf(hw.y, xl, 1.f));
        float rh1 = __builtin_amdgcn_rcpf(fmaf(hw.y, xh, 1.f));
        a0[2*i]   = fmaf(hw.z, rl0, a0[2*i]);
        a0[2*i+1] = fmaf(hw.z, rh0, a0[2*i+1]);
        a1[2*i]   = fmaf(hw.z, rl1, a1[2*i]);
        a1[2*i+1] = fmaf(hw.z, rh1, a1[2*i+1]);
    }
}
__device__ inline void wcproc2(uint4 c, float2 ap, float* acc0, float* acc1) {
    u32 cc[4] = {c.x, c.y, c.z, c.w};
    #pragma unroll
    for (int i = 0; i < 4; ++i) {
        float el = __uint_as_float(cc[i] << 16);
        float eh = __uint_as_float(cc[i] & 0xFFFF0000u);
        acc0[2*i]   = fmaf(ap.x, el, acc0[2*i]);
        acc0[2*i+1] = fmaf(ap.x, eh, acc0[2*i+1]);
        acc1[2*i]   = fmaf(ap.y, el, acc1[2*i]);
        acc1[2*i+1] = fmaf(ap.y, eh, acc1[2*i+1]);
    }
}

__global__ __launch_bounds__(1024) void energies(
    const float* __restrict__ maskp, const float* __restrict__ hp,
    const u16* __restrict__ ept, const float* __restrict__ Wv,
    const float* __restrict__ bvp, const u16* __restrict__ enc_bf,
    float* __restrict__ attn, float* __restrict__ wc)
{
    __shared__ __align__(16) float4 hpw[512];   // (e^{2hp_t0}, e^{2hp_t1}, Wv, -) 8KB
    __shared__ float pa[2][16][512];            // 64KB partials; reused for wc
    __shared__ float aL[512][2];                // 4KB attn weights for wc
    __shared__ float red[16];
    const int tid = threadIdx.x;
    const int b  = blockIdx.x & 7;              // XCD-grouped
    const int t0 = (blockIdx.x >> 3) * 2;
    const int th = tid >> 9;                    // 0: waves 0-7 (t0), 1: waves 8-15 (t0+1)
    const int k5 = tid & 511;
    const long long row0 = (long long)(b * 128 + t0) * 512;

    // ---- setup: hpw + sumWv ----
    float hv = hp[row0 + (long long)th * 512 + k5];
    float eh = __builtin_amdgcn_exp2f(hv);
    float* hpwf = (float*)hpw;
    hpwf[k5 * 4 + th] = eh;
    float w = 0.f;
    if (th == 0) { w = Wv[k5]; hpwf[k5 * 4 + 2] = w; }
    float wsum = wred_sum(w);
    if ((tid & 63) == 0) red[tid >> 6] = wsum;  // th==1 waves write 0: harmless
    __syncthreads();                            // hpw + red visible
    float sumWv = 0.f;
    #pragma unroll
    for (int i = 0; i < 16; ++i) sumWv += red[i];

    // ---- main loop: A[s] = sum_k Wv_k / (e^{2hp}*e^{2ep} + 1), both t ----
    const int kg = tid >> 6, sl = tid & 63;     // kg = wave: 32 k-rows; 8 s-cols
    const int s0 = sl * 8;
    const u16* eb = ept + (long long)b * 262144 + (kg * 32) * 512 + s0;
    const float4* hq = &hpw[kg * 32];

    float a0[8] = {0,0,0,0,0,0,0,0}, a1[8] = {0,0,0,0,0,0,0,0};
    uint4 c0 = *(const uint4*)(eb);
    uint4 c1 = *(const uint4*)(eb + 512);
    for (int kk = 0; kk < 30; kk += 2) {
        const u16* nb = eb + (kk + 2) * 512;
        uint4 n0 = *(const uint4*)(nb);
        uint4 n1 = *(const uint4*)(nb + 512);
        proc8(c0, hq[kk],     a0, a1);
        proc8(c1, hq[kk + 1], a0, a1);
        c0 = n0; c1 = n1;
    }
    proc8(c0, hq[30], a0, a1);
    proc8(c1, hq[31], a0, a1);

    *(float4*)&pa[0][kg][s0]     = make_float4(a0[0], a0[1], a0[2], a0[3]);
    *(float4*)&pa[0][kg][s0 + 4] = make_float4(a0[4], a0[5], a0[6], a0[7]);
    *(float4*)&pa[1][kg][s0]     = make_float4(a1[0], a1[1], a1[2], a1[3]);
    *(float4*)&pa[1][kg][s0 + 4] = make_float4(a1[4], a1[5], a1[6], a1[7]);
    __syncthreads();

    // ---- softmax: thread owns (t = th, s = k5); each wave is one th ----
    float A = 0.f;
    #pragma unroll
    for (int g = 0; g < 16; ++g) A += pa[th][g][k5];   // stride-1 lanes
    float mv = maskp[(long long)b * 512 + k5];
    float bv0 = bvp[0];
    float r = (bv0 + sumWv - 2.f * A) * mv; r *= mv;

    float vmax = wred_max(r);
    if ((tid & 63) == 0) red[tid >> 6] = vmax;  // sumWv reads were pre-barrier
    __syncthreads();
    float mx = red[th * 8];
    #pragma unroll
    for (int i = 1; i < 8; ++i) mx = fmaxf(mx, red[th * 8 + i]);

    float ex = __builtin_amdgcn_exp2f((r - mx) * LOG2E) * mv;
    float vsum = wred_sum(ex);
    __syncthreads();                            // mx reads done before red reuse
    if ((tid & 63) == 0) red[tid >> 6] = vsum;
    __syncthreads();
    float sm = 0.f;
    #pragma unroll
    for (int i = 0; i < 8; ++i) sm += red[th * 8 + i];
    float at = ex * (1.f / (sm + 1e-6f));
    attn[row0 + (long long)th * 512 + k5] = at;
    aL[k5][th] = at;
    __syncthreads();                            // aL visible; pa free for reuse

    // ---- wc = attn @ enc: thread owns 8 e-cols (eg) x 32 s-rows (sg) ----
    const int eg = tid & 63, sg = tid >> 6;
    const u16* encb = enc_bf + (long long)b * 262144 + (long long)(sg * 32) * 512 + eg * 8;
    const float2* aq = (const float2*)&aL[sg * 32][0];
    float acc0[8] = {0,0,0,0,0,0,0,0}, acc1[8] = {0,0,0,0,0,0,0,0};
    uint4 e0 = *(const uint4*)(encb);
    uint4 e1 = *(const uint4*)(encb + 512);
    for (int j = 0; j < 30; j += 2) {
        uint4 f0 = *(const uint4*)(encb + (long long)(j + 2) * 512);
        uint4 f1 = *(const uint4*)(encb + (long long)(j + 3) * 512);
        wcproc2(e0, aq[j],     acc0, acc1);
        wcproc2(e1, aq[j + 1], acc0, acc1);
        e0 = f0; e1 = f1;
    }
    wcproc2(e0, aq[30], acc0, acc1);
    wcproc2(e1, aq[31], acc0, acc1);

    *(float4*)&pa[0][sg][eg * 8]     = make_float4(acc0[0], acc0[1], acc0[2], acc0[3]);
    *(float4*)&pa[0][sg][eg * 8 + 4] = make_float4(acc0[4], acc0[5], acc0[6], acc0[7]);
    *(float4*)&pa[1][sg][eg * 8]     = make_float4(acc1[0], acc1[1], acc1[2], acc1[3]);
    *(float4*)&pa[1][sg][eg * 8 + 4] = make_float4(acc1[4], acc1[5], acc1[6], acc1[7]);
    __syncthreads();

    float wcv = 0.f;
    #pragma unroll
    for (int g = 0; g < 16; ++g) wcv += pa[th][g][k5];
    wc[row0 + (long long)th * 512 + k5] = wcv;
}

// =============== hout: h_tilde = tanh(wc @ Wout[:,:512]^T + hh) ==============
// Register-prefetch pipelined like proj. Wout read fp32 with inline pkcvt.
__global__ __launch_bounds__(256) void hout_k(
    const float* __restrict__ wc, const float* __restrict__ Wout,
    float* __restrict__ out)
{
    __shared__ u16 lA[32 * LAS];
    __shared__ u16 lB[64 * LAS];
    const int tid = threadIdx.x;
    const int wvi = tid >> 6, ln = tid & 63;
    const int l16 = ln & 15, quad = ln >> 4;
    const int msub = wvi & 1, npair = wvi >> 1;
    const int m0 = blockIdx.y * 32, n0 = blockIdx.x * 64;
    const int rowA = tid >> 3, kofA = (tid & 7) * 4;
    const int rowB = tid >> 2, kofB = (tid & 3) * 8;
    const float* Apw = wc + (long long)(m0 + rowA) * 512 + kofA;
    const float* Bpw = Wout + (long long)(n0 + rowB) * 1024 + kofB;
    f32x4 acc0 = {0,0,0,0}, acc1 = {0,0,0,0};

    float4 av, bw0, bw1;
    av  = *(const float4*)(Apw);
    bw0 = *(const float4*)(Bpw);
    bw1 = *(const float4*)(Bpw + 4);
    for (int k0 = 0; k0 < 512; k0 += 32) {
        uint2 aw = make_uint2(pkcvt(av.x, av.y), pkcvt(av.z, av.w));
        uint4 bv = make_uint4(pkcvt(bw0.x, bw0.y), pkcvt(bw0.z, bw0.w),
                              pkcvt(bw1.x, bw1.y), pkcvt(bw1.z, bw1.w));
        __syncthreads();
        *(uint2*)&lA[rowA * LAS + kofA] = aw;
        int kk = kofB ^ (((rowB >> 3) & 3) << 3);
        *(uint4*)&lB[rowB * LAS + kk] = bv;
        __syncthreads();
        if (k0 < 480) {
            av  = *(const float4*)(Apw + k0 + 32);
            bw0 = *(const float4*)(Bpw + k0 + 32);
            bw1 = *(const float4*)(Bpw + k0 + 36);
        }
        bf16x8 a = *(const bf16x8*)&lA[(msub * 16 + l16) * LAS + quad * 8];
        int nr0 = npair * 32 + l16, nr1 = nr0 + 16;
        bf16x8 b0 = *(const bf16x8*)&lB[nr0 * LAS + (quad * 8 ^ (((nr0 >> 3) & 3) << 3))];
        bf16x8 b1 = *(const bf16x8*)&lB[nr1 * LAS + (quad * 8 ^ (((nr1 >> 3) & 3) << 3))];
        acc0 = __builtin_amdgcn_mfma_f32_16x16x32_bf16(a, b0, acc0, 0, 0, 0);
        acc1 = __builtin_amdgcn_mfma_f32_16x16x32_bf16(a, b1, acc1, 0, 0, 0);
    }
    #pragma unroll
    for (int j = 0; j < 2; ++j) {
        const f32x4& a = j ? acc1 : acc0;
        #pragma unroll
        for (int r = 0; r < 4; ++r) {
            int m = m0 + msub * 16 + quad * 4 + r;
            int n = n0 + npair * 32 + j * 16 + l16;
            long long idx = (long long)m * 512 + n;
            out[idx] = tanh_fast(a[r] + out[idx]);   // out[idx] holds hh
        }
    }
}

extern "C" void kernel_launch(void* const* d_in, const int* in_sizes, int n_in,
                              void* d_out, int out_size, void* d_ws, size_t ws_size,
                              hipStream_t stream)
{
    const float* hidden = (const float*)d_in[0];  // (8,128,512)
    const float* enc    = (const float*)d_in[1];  // (8,512,512)
    const float* mask   = (const float*)d_in[2];  // (8,512)
    const float* Wattn  = (const float*)d_in[3];  // (512,1024)
    const float* battn  = (const float*)d_in[4];  // (512,)
    const float* Wv     = (const float*)d_in[5];  // (512,)
    const float* bvp    = (const float*)d_in[6];  // (1,)
    const float* Wout   = (const float*)d_in[7];  // (512,1024)
    float* out = (float*)d_out;

    float* hp     = (float*)d_ws;                     // @0   2MB fp32
    u16*   ept    = (u16*)((char*)d_ws + (2 << 20));  // @2M  4MB bf16 (exp2 domain)
    u16*   enc_bf = (u16*)((char*)d_ws + (6 << 20));  // @6M  4MB bf16

    proj<<<768, 256, 0, stream>>>(hidden, enc, Wattn, battn, Wout,
                                  hp, ept, out /* hh in-place */, enc_bf);
    energies<<<512, 1024, 0, stream>>>(mask, hp, ept, Wv, bvp, enc_bf,
                                       out + OUT_ATTN, out + OUT_WC);
    hout_k<<<dim3(8, 32, 1), 256, 0, stream>>>(out + OUT_WC, Wout, out);
}